// Round 3
// baseline (691.322 us; speedup 1.0000x reference)
//
#include <hip/hip_runtime.h>
#include <math.h>

// FFM forward, pair-major restructure (R3).
//
// interaction(b) = sum_{i<j} dot(W[j, g(b,i)], W[i, g(b,j)]),  g(b,f)=x[b,f]+f*5000.
//
// Key insight: pair (i,j) only touches two 1.28MB windows of the 512MB W.
// Process work pair-group-major with a persistent 512-block grid so the
// instantaneous working set is ~16 groups x 10.2MB = 164MB < 256MB L3:
// the 1.64x row reuse across samples then hits L3, and HBM fetch drops to
// the unique footprint (~392MB) instead of the 797MB demand.

#define FF 20
#define V_FIELD 5000
#define TOT (FF * V_FIELD)     // 100000
#define DD 64
#define NB 8192                // batch
#define NP 190                 // unordered pairs
#define GPG 4                  // pairs per group
#define NG 48                  // ceil(190/4), last group has 2 pads
#define SCH 256                // samples per chunk
#define NCH (NB / SCH)         // 32
#define NWORK (NG * NCH)       // 1536
#define GRID 512               // persistent blocks; NWORK % GRID == 0

__global__ __launch_bounds__(256) void ffm_pairs(
    const int* __restrict__ x,
    const float* __restrict__ W,
    float* __restrict__ acc)
{
    __shared__ short pi[GPG * NG], pj[GPG * NG];
    __shared__ int gidx[SCH * FF];          // 20KB: staged g(b,f) for the chunk

    const int t = threadIdx.x;

    // Pair table (i<j); pads (p>=190) guarded at use.
    if (t < GPG * NG) {
        int pp = (t >= NP) ? 0 : t;
        int i = 0;
        while (pp >= FF - 1 - i) { pp -= FF - 1 - i; ++i; }
        pi[t] = (short)i;
        pj[t] = (short)(i + 1 + pp);
    }

    const int wv   = t >> 6;                // wave 0..3 -> samples wv*64..+63
    const int ln   = t & 63;
    const int grp  = ln >> 4;               // 4 sample-slots per wave-instr
    const int sub  = ln & 15;               // float4 chunk within 256B row
    const char* Wb = (const char*)W;

    // Work-items group-major: consecutive blockIdx -> same pair-group,
    // different sample-chunk. 512 resident blocks span ~16 groups.
    for (int w = blockIdx.x; w < NWORK; w += GRID) {
        const int g_id  = w / NCH;
        const int chunk = w % NCH;

        __syncthreads();                    // protect gidx from prev iter
        // Stage g(b,f) for this chunk's 256 samples (coalesced).
        for (int k = t; k < SCH * FF; k += 256) {
            const int f = k % FF;
            gidx[k] = x[chunk * (SCH * FF) + k] + f * V_FIELD;
        }
        __syncthreads();

#pragma unroll 2
        for (int q = 0; q < 16; ++q) {      // 16 sample-quads per wave
            const int sl = wv * 64 + q * 4 + grp;   // sample within chunk
            float4 a4 = make_float4(0.f, 0.f, 0.f, 0.f);
#pragma unroll
            for (int k = 0; k < GPG; ++k) {
                const int p = g_id * GPG + k;       // wave-uniform
                if (p < NP) {
                    const int i = pi[p], j = pj[p];
                    const unsigned ga = (unsigned)gidx[sl * FF + i];
                    const unsigned gb = (unsigned)gidx[sl * FF + j];
                    const float4 va = *(const float4*)
                        (Wb + (((unsigned)(j * TOT) + ga) << 8) + sub * 16);
                    const float4 vb = *(const float4*)
                        (Wb + (((unsigned)(i * TOT) + gb) << 8) + sub * 16);
                    a4.x = fmaf(va.x, vb.x, a4.x);
                    a4.y = fmaf(va.y, vb.y, a4.y);
                    a4.z = fmaf(va.z, vb.z, a4.z);
                    a4.w = fmaf(va.w, vb.w, a4.w);
                }
            }
            float s = (a4.x + a4.y) + (a4.z + a4.w);
            // Reduce the 16 lanes holding this sample's 64 dims.
            s += __shfl_xor(s, 1, 64);
            s += __shfl_xor(s, 2, 64);
            s += __shfl_xor(s, 4, 64);
            s += __shfl_xor(s, 8, 64);
            if (sub == 0)
                atomicAdd(&acc[chunk * SCH + sl], s);
        }
    }
}

__global__ __launch_bounds__(256) void ffm_finish(
    const int* __restrict__ x,
    const float* __restrict__ Wl,
    const float* __restrict__ bias,
    const float* __restrict__ acc,
    float* __restrict__ out)
{
    const int b = blockIdx.x * 256 + threadIdx.x;
    float s = acc[b];
    const int* xr = x + b * FF;
#pragma unroll
    for (int f = 0; f < FF; ++f)
        s += Wl[xr[f] + f * V_FIELD];
    out[b] = 1.f / (1.f + expf(-(s + bias[0])));
}

extern "C" void kernel_launch(void* const* d_in, const int* in_sizes, int n_in,
                              void* d_out, int out_size, void* d_ws, size_t ws_size,
                              hipStream_t stream) {
    const int*   x    = (const int*)d_in[0];
    const float* W    = (const float*)d_in[1];
    const float* Wl   = (const float*)d_in[2];
    const float* bias = (const float*)d_in[3];
    float* out = (float*)d_out;
    float* acc = (float*)d_ws;              // 8192 floats of the 2GB ws

    hipMemsetAsync(acc, 0, NB * sizeof(float), stream);
    hipLaunchKernelGGL(ffm_pairs, dim3(GRID), dim3(256), 0, stream, x, W, acc);
    hipLaunchKernelGGL(ffm_finish, dim3(NB / 256), dim3(256), 0, stream,
                       x, Wl, bias, acc, out);
}

// Round 4
// 663.409 us; speedup vs baseline: 1.0421x; 1.0421x over previous
//
#include <hip/hip_runtime.h>
#include <math.h>

// FFM forward, R4: L3-window ordering at full parallelism.
//
// interaction(b) = sum_{i<j} dot(W[j,g(b,i)], W[i,g(b,j)]), g(b,f)=x[b,f]+f*5000.
//
// 2048 blocks (R2's proven MLP level). block -> (set = blk/128 in [0,16),
// chunk = blk%128 of 64 samples). Each block sweeps pair-groups
// g = set, set+16, set+32 (4 pairs each) for its fixed 64 samples,
// accumulating in registers. All resident blocks progress item-major, so the
// instantaneous W window is 16 groups x 10.2MB = 163MB < 256MB L3: the 1.64x
// cross-sample row reuse should be served by L3 instead of HBM.

#define FF 20
#define V_FIELD 5000
#define TOT (FF * V_FIELD)     // 100000
#define NB 8192
#define NP 190
#define GPG 4                  // pairs per group
#define NG 48                  // groups (2 pad pairs)
#define SPB 64                 // samples per block
#define NCH (NB / SPB)         // 128 chunks
#define NSET 16                // concurrent group-sets
#define NITEM (NG / NSET)      // 3 groups per block
#define GRID (NCH * NSET)      // 2048 blocks

__global__ __launch_bounds__(256, 4) void ffm_pairs(
    const int* __restrict__ x,
    const float* __restrict__ W,
    float* __restrict__ acc)
{
    __shared__ short pi[GPG * NG], pj[GPG * NG];
    __shared__ int gidx[SPB * FF];          // 5KB: g(b,f) for this chunk

    const int t = threadIdx.x;

    // Pair table (i<j); pads guarded at use.
    if (t < GPG * NG) {
        int pp = (t >= NP) ? 0 : t;
        int i = 0;
        while (pp >= FF - 1 - i) { pp -= FF - 1 - i; ++i; }
        pi[t] = (short)i;
        pj[t] = (short)(i + 1 + pp);
    }

    const int set = blockIdx.x >> 7;        // group-set 0..15
    const int c   = blockIdx.x & (NCH - 1); // sample chunk 0..127

    // Stage g(b,f) for this chunk's 64 samples (coalesced, once).
    for (int k = t; k < SPB * FF; k += 256) {
        const int f = k % FF;
        gidx[k] = x[c * (SPB * FF) + k] + f * V_FIELD;
    }
    __syncthreads();

    const int wv  = t >> 6;                 // wave -> samples wv*16..+15
    const int ln  = t & 63;
    const int grp = ln >> 4;                // sample within quad
    const int sub = ln & 15;                // float4 chunk within 256B row
    const char* Wb = (const char*)W;

    float4 a4[4];
#pragma unroll
    for (int q = 0; q < 4; ++q) a4[q] = make_float4(0.f, 0.f, 0.f, 0.f);

    for (int item = 0; item < NITEM; ++item) {
        const int g = set + item * NSET;    // all resident blocks on same 16 groups
#pragma unroll
        for (int q = 0; q < 4; ++q) {
            const int sl = wv * 16 + q * 4 + grp;
#pragma unroll
            for (int k = 0; k < GPG; ++k) {
                const int p = g * GPG + k;  // wave-uniform
                if (p < NP) {
                    const int i = pi[p], j = pj[p];
                    const unsigned ga = (unsigned)gidx[sl * FF + i];
                    const unsigned gb = (unsigned)gidx[sl * FF + j];
                    const float4 va = *(const float4*)
                        (Wb + (((unsigned)(j * TOT) + ga) << 8) + sub * 16);
                    const float4 vb = *(const float4*)
                        (Wb + (((unsigned)(i * TOT) + gb) << 8) + sub * 16);
                    a4[q].x = fmaf(va.x, vb.x, a4[q].x);
                    a4[q].y = fmaf(va.y, vb.y, a4[q].y);
                    a4[q].z = fmaf(va.z, vb.z, a4[q].z);
                    a4[q].w = fmaf(va.w, vb.w, a4[q].w);
                }
            }
        }
    }

    // Reduce the 16 sub-lanes holding each sample's 64 dims; one atomic
    // per sample per set (16 per sample total across the grid).
#pragma unroll
    for (int q = 0; q < 4; ++q) {
        float s = (a4[q].x + a4[q].y) + (a4[q].z + a4[q].w);
        s += __shfl_xor(s, 1, 64);
        s += __shfl_xor(s, 2, 64);
        s += __shfl_xor(s, 4, 64);
        s += __shfl_xor(s, 8, 64);
        if (sub == 0)
            atomicAdd(&acc[c * SPB + wv * 16 + q * 4 + grp], s);
    }
}

__global__ __launch_bounds__(256) void ffm_finish(
    const int* __restrict__ x,
    const float* __restrict__ Wl,
    const float* __restrict__ bias,
    const float* __restrict__ acc,
    float* __restrict__ out)
{
    const int b = blockIdx.x * 256 + threadIdx.x;
    float s = acc[b];
    const int* xr = x + b * FF;
#pragma unroll
    for (int f = 0; f < FF; ++f)
        s += Wl[xr[f] + f * V_FIELD];
    out[b] = 1.f / (1.f + expf(-(s + bias[0])));
}

extern "C" void kernel_launch(void* const* d_in, const int* in_sizes, int n_in,
                              void* d_out, int out_size, void* d_ws, size_t ws_size,
                              hipStream_t stream) {
    const int*   x    = (const int*)d_in[0];
    const float* W    = (const float*)d_in[1];
    const float* Wl   = (const float*)d_in[2];
    const float* bias = (const float*)d_in[3];
    float* out = (float*)d_out;
    float* acc = (float*)d_ws;              // 8192 floats of scratch

    hipMemsetAsync(acc, 0, NB * sizeof(float), stream);
    hipLaunchKernelGGL(ffm_pairs, dim3(GRID), dim3(256), 0, stream, x, W, acc);
    hipLaunchKernelGGL(ffm_finish, dim3(NB / 256), dim3(256), 0, stream,
                       x, Wl, bias, acc, out);
}